// Round 4
// baseline (235.069 us; speedup 1.0000x reference)
//
#include <hip/hip_runtime.h>
#include <math.h>

// CBOW hierarchical-softmax loss — R7: persistent waves + cross-example pipeline.
//   B=65536, C=10, D=18, E=128.
//   loss[b] = -sum_d log( p_d + 1e-9 ), p_d = (code==1) ? s_d : 1 - s_d,
//   s_d = sigmoid(u_d . v), v = mean_c in_embed[ctx[b,c]].
//
// R1: p computed literally as fp32 reference (s, then 1-s); precise expf/logf.
// R5: distributed transcendentals (VALUBusy 52->24%, dur flat -> memory-side).
// R6 post-mortem: inline-asm 14-deep gather cluster + split vmcnt waits ->
//   dur IDENTICAL (131.3 us) for the 3rd schedule variant. Per-wave latency
//   is NOT the limiter.
// R7 theory: workgroup turnover. 16384 WGs x ~2-4 us life = 125 WG/us launch
//   rate required — at the CP's ceiling; explains all pipes <50%, occupancy
//   73% despite VGPR=32, and insensitivity to intra-wave scheduling.
// Fix: persistent waves. 2048 blocks x 4 waves; each wave runs 8 consecutive
//   examples, software-pipelined: issue ex k+1's 14 gathers (asm), wait
//   vmcnt(14) (drains ex k's rows, leaves k+1's in flight), compute ex k.
//   One coalesced 8-lane store per wave at the end. Math bit-identical to
//   R5/R6. sched_barrier(0) after each waitcnt (rule #18).
// Discriminates: launch-limited (expect ~100-110 us) vs random-gather HBM
//   ceiling (flat -> declare roofline).

typedef float f32x4 __attribute__((ext_vector_type(4)));

constexpr int Bn = 65536;
constexpr int Cn = 10;
constexpr int Dn = 18;
constexpr int EXW = 8;                 // examples per wave
constexpr int NBLK = Bn / (4 * EXW);   // 2048 blocks
constexpr float EPS = 1e-9f;

// ---- load index set for example (b0+EX) into slot arrays; codes into cm[EX]
#define LOAD_IDX(C_, N_, EX)                                                 \
  {                                                                          \
    const int bb = b0 + (EX);                                                \
    const int* __restrict__ cp = ctx + bb * Cn;                              \
    const int* __restrict__ np = nodes + bb * Dn;                            \
    const int* __restrict__ kp = codes + bb * Dn;                            \
    _Pragma("unroll") for (int k = 0; k < Cn; ++k) C_[k] = cp[k];            \
    _Pragma("unroll") for (int k = 0; k < Dn; ++k) N_[k] = np[k];            \
    int ce = 0, co = 0;                                                      \
    _Pragma("unroll") for (int i = 0; i < Dn / 2; ++i) {                     \
      ce |= (kp[2 * i] == 1 ? 1 : 0) << i;                                   \
      co |= (kp[2 * i + 1] == 1 ? 1 : 0) << i;                               \
    }                                                                        \
    cmE[EX] = ce; cmO[EX] = co;                                              \
  }

// ---- issue the 14 row gathers for one example (halves take even/odd c,d)
#define ISSUE_GATHERS(C_, N_, E_, U_)                                        \
  {                                                                          \
    _Pragma("unroll") for (int k = 0; k < Cn / 2; ++k) {                     \
      const int idx = hi ? C_[2 * k + 1] : C_[2 * k];                        \
      const unsigned vo = ((unsigned)idx << 9) + vsl;                        \
      asm volatile("global_load_dwordx4 %0, %1, %2"                          \
                   : "=v"(E_[k]) : "v"(vo), "s"(in_base));                   \
    }                                                                        \
    _Pragma("unroll") for (int i = 0; i < Dn / 2; ++i) {                     \
      const int idx = hi ? N_[2 * i + 1] : N_[2 * i];                        \
      const unsigned vo = ((unsigned)idx << 9) + vsl;                        \
      asm volatile("global_load_dwordx4 %0, %1, %2"                          \
                   : "=v"(U_[i]) : "v"(vo), "s"(ne_base));                   \
    }                                                                        \
  }

// ---- full per-example math, bit-identical to R5/R6 (absmax 0.0) ----------
#define COMPUTE_LOSS(E_, U_, EX)                                             \
  {                                                                          \
    float vsx = 0.f, vsy = 0.f, vsz = 0.f, vsw = 0.f;                        \
    _Pragma("unroll") for (int k = 0; k < Cn / 2; ++k) {                     \
      vsx += E_[k].x; vsy += E_[k].y; vsz += E_[k].z; vsw += E_[k].w;        \
    }                                                                        \
    vsx += __shfl_xor(vsx, 32, 64);                                          \
    vsy += __shfl_xor(vsy, 32, 64);                                          \
    vsz += __shfl_xor(vsz, 32, 64);                                          \
    vsw += __shfl_xor(vsw, 32, 64);                                          \
    const float vx = vsx * (1.0f / Cn), vy = vsy * (1.0f / Cn);              \
    const float vz = vsz * (1.0f / Cn), vw = vsw * (1.0f / Cn);              \
    float pd[Dn / 2];                                                        \
    _Pragma("unroll") for (int i = 0; i < Dn / 2; ++i)                       \
      pd[i] = U_[i].x * vx + U_[i].y * vy + U_[i].z * vz + U_[i].w * vw;     \
    _Pragma("unroll") for (int i = 0; i < Dn / 2; ++i) {                     \
      _Pragma("unroll") for (int m = 16; m >= 1; m >>= 1)                    \
        pd[i] += __shfl_xor(pd[i], m, 64);                                   \
    }                                                                        \
    const int sel = lane & 15;                                               \
    const float x01 = (sel & 1) ? pd[1] : pd[0];                             \
    const float x23 = (sel & 1) ? pd[3] : pd[2];                             \
    const float x45 = (sel & 1) ? pd[5] : pd[4];                             \
    const float x67 = (sel & 1) ? pd[7] : pd[6];                             \
    const float x0123 = (sel & 2) ? x23 : x01;                               \
    const float x4567 = (sel & 2) ? x67 : x45;                               \
    const float xlow = (sel & 4) ? x4567 : x0123;                            \
    const float x = (sel & 8) ? pd[8] : xlow;                                \
    const int cm = hi ? cmO[EX] : cmE[EX];                                   \
    const int cd = (cm >> sel) & 1;                                          \
    const float s = 1.0f / (1.0f + expf(-x));                                \
    const float p = (cd == 1) ? s : 1.0f - s;                                \
    float loss = (sel < Dn / 2) ? -logf(p + EPS) : 0.0f;                     \
    loss += __shfl_xor(loss, 1, 64);                                         \
    loss += __shfl_xor(loss, 2, 64);                                         \
    loss += __shfl_xor(loss, 4, 64);                                         \
    loss += __shfl_xor(loss, 8, 64);                                         \
    loss += __shfl_xor(loss, 32, 64);                                        \
    res[EX] = loss;                                                          \
  }

#define WAIT14()                                                             \
  asm volatile("s_waitcnt vmcnt(14)" ::: "memory");                          \
  __builtin_amdgcn_sched_barrier(0);

#define WAIT0()                                                              \
  asm volatile("s_waitcnt vmcnt(0)" ::: "memory");                           \
  __builtin_amdgcn_sched_barrier(0);

__global__ __launch_bounds__(256) void cbow_hs_kernel(
    const int* __restrict__ ctx,          // [B,C]
    const int* __restrict__ nodes,        // [B,D]
    const int* __restrict__ codes,        // [B,D]
    const float* __restrict__ in_embed,   // [V,E]
    const float* __restrict__ node_embed, // [N,E]
    float* __restrict__ out)              // [B]
{
    const int lane = threadIdx.x & 63;
    const int sl   = lane & 31;          // sub-lane within half
    const bool hi  = lane >= 32;         // which half
    // wave id uniform -> SGPR; index loads select as scalar (SMEM) loads.
    int w = (int)(blockIdx.x << 2) + (int)(threadIdx.x >> 6);
    w = __builtin_amdgcn_readfirstlane(w);
    const int b0 = w * EXW;              // this wave owns examples b0..b0+7

    const unsigned long long in_base = (unsigned long long)in_embed;
    const unsigned long long ne_base = (unsigned long long)node_embed;
    const unsigned vsl = (unsigned)sl << 4;

    int cA[Cn], nA[Dn];                  // index slot A (even examples)
    int cB[Cn], nB[Dn];                  // index slot B (odd examples)
    int cmE[EXW], cmO[EXW];              // per-example packed codes
    f32x4 eA[Cn / 2], uA[Dn / 2];        // row buffers, double-buffered
    f32x4 eB[Cn / 2], uB[Dn / 2];
    float res[EXW];

    // ---- prologue: fill the pipe -----------------------------------------
    LOAD_IDX(cA, nA, 0)
    ISSUE_GATHERS(cA, nA, eA, uA)        // ex0 in flight
    LOAD_IDX(cB, nB, 1)

    // ---- steady state: issue ex k+1, wait for ex k, compute ex k ---------
    ISSUE_GATHERS(cB, nB, eB, uB)        // ex1 in flight (28 outstanding)
    LOAD_IDX(cA, nA, 2)
    WAIT14()                             // ex0 landed
    COMPUTE_LOSS(eA, uA, 0)

    ISSUE_GATHERS(cA, nA, eA, uA)        // ex2
    LOAD_IDX(cB, nB, 3)
    WAIT14()                             // ex1 landed
    COMPUTE_LOSS(eB, uB, 1)

    ISSUE_GATHERS(cB, nB, eB, uB)        // ex3
    LOAD_IDX(cA, nA, 4)
    WAIT14()                             // ex2 landed
    COMPUTE_LOSS(eA, uA, 2)

    ISSUE_GATHERS(cA, nA, eA, uA)        // ex4
    LOAD_IDX(cB, nB, 5)
    WAIT14()                             // ex3 landed
    COMPUTE_LOSS(eB, uB, 3)

    ISSUE_GATHERS(cB, nB, eB, uB)        // ex5
    LOAD_IDX(cA, nA, 6)
    WAIT14()                             // ex4 landed
    COMPUTE_LOSS(eA, uA, 4)

    ISSUE_GATHERS(cA, nA, eA, uA)        // ex6
    LOAD_IDX(cB, nB, 7)
    WAIT14()                             // ex5 landed
    COMPUTE_LOSS(eB, uB, 5)

    ISSUE_GATHERS(cB, nB, eB, uB)        // ex7
    WAIT14()                             // ex6 landed
    COMPUTE_LOSS(eA, uA, 6)

    WAIT0()                              // ex7 landed (pipe drained)
    COMPUTE_LOSS(eB, uB, 7)

    // ---- epilogue: one coalesced 8-lane store per wave -------------------
    // res[i] identical across all lanes; lane q<8 stores res[q].
    const int q = lane & 7;
    const float r01 = (q & 1) ? res[1] : res[0];
    const float r23 = (q & 1) ? res[3] : res[2];
    const float r45 = (q & 1) ? res[5] : res[4];
    const float r67 = (q & 1) ? res[7] : res[6];
    const float r03 = (q & 2) ? r23 : r01;
    const float r47 = (q & 2) ? r67 : r45;
    const float r   = (q & 4) ? r47 : r03;
    if (lane < 8) out[b0 + lane] = r;
}

extern "C" void kernel_launch(void* const* d_in, const int* in_sizes, int n_in,
                              void* d_out, int out_size, void* d_ws, size_t ws_size,
                              hipStream_t stream) {
    const int*   ctx        = (const int*)d_in[0];
    const int*   path_nodes = (const int*)d_in[1];
    const int*   codes      = (const int*)d_in[2];
    const float* in_embed   = (const float*)d_in[3];
    const float* node_embed = (const float*)d_in[4];
    float*       out        = (float*)d_out;

    dim3 grid(NBLK);
    dim3 block(256);
    cbow_hs_kernel<<<grid, block, 0, stream>>>(ctx, path_nodes, codes,
                                               in_embed, node_embed, out);
}